// Round 6
// baseline (1722.957 us; speedup 1.0000x reference)
//
#include <hip/hip_runtime.h>

#define MAX_ITER 8192
#define NCHUNK   128
#define NCHUNKS  64           // MAX_ITER / NCHUNK
#define NSCAN    64           // scanner blocks, 2 samples each
#define NTHREADS 256

typedef unsigned long long u64;
#define KEY_MAX  0xffffffffffffffffull
#define POISON64 0xAAAAAAAAAAAAAAAAull   // d_ws re-poison pattern (0xAA bytes)

// IEEE fp32 ops, contraction off -> bitwise numpy match (verified rounds 0-5).
__device__ __forceinline__ float mul_rn(float a, float b) {
#pragma clang fp contract(off)
  return a * b;
}
__device__ __forceinline__ float add_rn(float a, float b) {
#pragma clang fp contract(off)
  return a + b;
}
__device__ __forceinline__ float sub_rn(float a, float b) {
#pragma clang fp contract(off)
  return a - b;
}
__device__ __forceinline__ float dist2(float px, float py, float sx, float sy) {
  const float dx = sub_rn(px, sx), dy = sub_rn(py, sy);
  return add_rn(mul_rn(dx, dx), mul_rn(dy, dy));
}
// steer: exact reference math; depends only on final (bd2,bx,by,s)
__device__ __forceinline__ void steer(float sx, float sy, float bd2, float bx,
                                      float by, float& nx, float& ny) {
  const float dirx = sub_rn(sx, bx), diry = sub_rn(sy, by);
  const float dist = __fsqrt_rn(add_rn(bd2, 1e-12f));
  const float scl = (dist > 5.0f) ? __fdiv_rn(5.0f, dist) : 1.0f;
  nx = add_rn(bx, mul_rn(dirx, scl));
  ny = add_rn(by, mul_rn(diry, scl));
}
__device__ __forceinline__ float bcastf(float v, int lane) {
  return __int_as_float(__builtin_amdgcn_readlane(__float_as_int(v), lane));
}
__device__ __forceinline__ void st_agent(u64* p, u64 v) {
  __hip_atomic_store(p, v, __ATOMIC_RELAXED, __HIP_MEMORY_SCOPE_AGENT);
}
__device__ __forceinline__ u64 ld_agent(u64* p) {
  return __hip_atomic_load(p, __ATOMIC_RELAXED, __HIP_MEMORY_SCOPE_AGENT);
}
__device__ __forceinline__ u64 packf2(float x, float y) {
  return ((u64)__float_as_uint(y) << 32) | (u64)__float_as_uint(x);
}
__device__ __forceinline__ float lo32f(u64 v) {
  return __uint_as_float((unsigned)(v & 0xffffffffu));
}
__device__ __forceinline__ float hi32f(u64 v) {
  return __uint_as_float((unsigned)(v >> 32));
}
__device__ __forceinline__ void compiler_fence() {
  asm volatile("" ::: "memory");
}
// Exact (d2, idx) lex key: d2>=0 -> bit-monotone; ties -> lowest idx.
// Scanner keys: idx bits 0..12 (max idx 7808), tag bits 13..20 (131..191;
// 0xAA poison decodes to tag 85 -> can never false-match).
__device__ __forceinline__ u64 mkkey(float d2, int idx) {
  return ((u64)__float_as_uint(d2) << 32) | (u64)(unsigned)idx;
}
__device__ __forceinline__ unsigned tagof(u64 kv) {
  return ((unsigned)(kv >> 13)) & 0xFFu;
}
// carry fold: index-form (coords resolved at merge via one Nb gather)
__device__ __forceinline__ void cfold(float d, unsigned idx, float& cd, unsigned& ci) {
  if (d < cd) { cd = d; ci = idx; }
}

__global__ __launch_bounds__(NTHREADS) void rrt_kernel(
    const float* __restrict__ state, const float* __restrict__ goal,
    const float* __restrict__ u, const float* __restrict__ r,
    float* __restrict__ out, unsigned* __restrict__ ws) {
  __shared__ u64 wkey[4][2];            // scanner per-wave reduce slots

  u64* outU  = (u64*)out;               // node i at outU[i] (float2-packed)
  // MbufK: 4-slot ring x 128 tagged keys.  Scanner iter i writes slot i&3,
  // tag i+131: per-sample argmin over [0..128(i+1)] vs chunk (i+3)'s samples.
  // Coordinator merge j (>=3) reads slot (j-3)&3 requiring tag == j+128
  // EXACTLY (sample-specific, r3 lesson).  Slot reuse (iter i+4) needs Nb
  // chunk i+4, published only after merge j=i+3 consumed iter i's M.
  u64* MbufK = (u64*)(ws + 64);         // bytes 256..4351
  u64* Nb    = (u64*)(ws + 1088);       // bytes 4352..69887
  // Nb[m] = node m+1, written ONCE; 0xAA poison is an impossible node value.
  // Data IS the ready flag -> no drain, no init guard.  All Nb reads use
  // agent-scope loads (MALL coherence point) -> no stale-L1 hazard.

  const int tid  = threadIdx.x;
  const int wave = tid >> 6;
  const int lane = tid & 63;
  const int blk  = blockIdx.x;

  const float n0x = state[0], n0y = state[1];
  const float gx = goal[0],  gy = goal[1];

  if (blk == 0) {
    // ================= coordinator: single wave ==================
    if (wave != 0) return;
    if (lane == 0) st_agent(&outU[0], packf2(n0x, n0y));   // node 0

    // samples: state A = chunk sample lane, state B = sample 64+lane
    float sAx, sAy, sBx, sBy, s1Ax, s1Ay, s1Bx, s1By;
    {
      const float uu = u[lane];
      if (uu < 0.1f) { sAx = gx; sAy = gy; }
      else { sAx = mul_rn(r[2 * lane], 200.0f); sAy = mul_rn(r[2 * lane + 1], 200.0f); }
      const int ib = 64 + lane;
      const float ub = u[ib];
      if (ub < 0.1f) { sBx = gx; sBy = gy; }
      else { sBx = mul_rn(r[2 * ib], 200.0f); sBy = mul_rn(r[2 * ib + 1], 200.0f); }
      const int i1a = NCHUNK + lane;
      const float u1a = u[i1a];
      if (u1a < 0.1f) { s1Ax = gx; s1Ay = gy; }
      else { s1Ax = mul_rn(r[2 * i1a], 200.0f); s1Ay = mul_rn(r[2 * i1a + 1], 200.0f); }
      const int i1b = NCHUNK + 64 + lane;
      const float u1b = u[i1b];
      if (u1b < 0.1f) { s1Bx = gx; s1By = gy; }
      else { s1Bx = mul_rn(r[2 * i1b], 200.0f); s1By = mul_rn(r[2 * i1b + 1], 200.0f); }
    }
    // 2-deep carries (index-form).  At merge j, c1 covers chunks j-2, j-1
    // (folded ascending: j-2's nodes as c2 during chunk j-2, then j-1's as
    // c1 during chunk j-1 -> strict < keeps lowest index on ties).
    float cA1d = 3.0e38f, cB1d = 3.0e38f, cA2d = 3.0e38f, cB2d = 3.0e38f;
    unsigned cA1i = 0, cB1i = 0, cA2i = 0, cB2i = 0;
    u64 kvPreA = 0, kvPreB = 0;

    for (int j = 0; j < NCHUNKS; ++j) {
      const int c = j * NCHUNK;

      // prefetch chunk j+2 samples (becomes s1 next chunk)
      float s2Ax = 0.0f, s2Ay = 0.0f, s2Bx = 0.0f, s2By = 0.0f;
      if (j + 2 < NCHUNKS) {
        const int ia = (j + 2) * NCHUNK + lane;
        const float ua = u[ia];
        if (ua < 0.1f) { s2Ax = gx; s2Ay = gy; }
        else { s2Ax = mul_rn(r[2 * ia], 200.0f); s2Ay = mul_rn(r[2 * ia + 1], 200.0f); }
        const int ib = ia + 64;
        const float ub = u[ib];
        if (ub < 0.1f) { s2Bx = gx; s2By = gy; }
        else { s2Bx = mul_rn(r[2 * ib], 200.0f); s2By = mul_rn(r[2 * ib + 1], 200.0f); }
      }

      // ---- merge argmin over [0..128j] per state:
      //   M (j>=3): [0..128(j-2)], M wins ties (lower indices)
      //   c1: chunks j-2, j-1  (disjoint higher range, strict <)
      float bAd, bBd; unsigned bAi, bBi;    // idx 0 -> node 0
      if (j >= 3) {
        const unsigned want = (unsigned)(j + 128);
        u64 kA = kvPreA, kB = kvPreB;
        if (!__all((int)((tagof(kA) == want) & (tagof(kB) == want)))) {
          u64* slot = MbufK + (((unsigned)(j - 3)) & 3u) * NCHUNK;
          for (;;) {
            kA = ld_agent(&slot[lane]);
            kB = ld_agent(&slot[64 + lane]);
            if (__all((int)((tagof(kA) == want) & (tagof(kB) == want)))) break;
            __builtin_amdgcn_s_sleep(1);
          }
        }
        compiler_fence();
        bAd = hi32f(kA); bAi = (unsigned)kA & 0x1FFFu;
        bBd = hi32f(kB); bBi = (unsigned)kB & 0x1FFFu;
      } else {
        bAd = dist2(n0x, n0y, sAx, sAy); bAi = 0u;
        bBd = dist2(n0x, n0y, sBx, sBy); bBi = 0u;
      }
      if (cA1d < bAd) { bAd = cA1d; bAi = cA1i; }
      if (cB1d < bBd) { bBd = cB1d; bBi = cB1i; }
      // winner-coords gathers (own prior agent stores; issue early)
      const u64 wvA = ld_agent(&Nb[(bAi ? bAi : 1u) - 1u]);
      const u64 wvB = ld_agent(&Nb[(bBi ? bBi : 1u) - 1u]);

      // carry shift; fresh c2
      cA1d = cA2d; cA1i = cA2i; cB1d = cB2d; cB1i = cB2i;
      cA2d = 3.0e38f; cA2i = 0; cB2d = 3.0e38f; cB2i = 0;

      // speculative ring loads for merge j+1 (slot (j-2)&3); ~1 chunk in flight
      if (j >= 2 && j + 1 < NCHUNKS) {
        u64* ns = MbufK + (((unsigned)(j - 2)) & 3u) * NCHUNK;
        kvPreA = ld_agent(&ns[lane]);
        kvPreB = ld_agent(&ns[64 + lane]);
      }

      float bxA, byA, bxB, byB;
      bxA = bAi ? lo32f(wvA) : n0x;  byA = bAi ? hi32f(wvA) : n0y;
      bxB = bBi ? lo32f(wvB) : n0x;  byB = bBi ? hi32f(wvB) : n0y;

      float bd2A = bAd, bd2B = bBd;
      float nxA, nyA, nxB, nyB;
      steer(sAx, sAy, bd2A, bxA, byA, nxA, nyA);
      steer(sBx, sBy, bd2B, bxB, byB, nxB, nyB);

      // ---- A-half: steps t=0..63, broadcasts from state A ----
      #pragma unroll
      for (int g = 0; g < 8; ++g) {
        const int gg = g * 8;
        float qx[8], qy[8], da[8], db[8];
        #pragma unroll
        for (int jj = 0; jj < 8; ++jj) {
          qx[jj] = bcastf(nxA, gg + jj);     // node c+gg+jj+1 (speculative)
          qy[jj] = bcastf(nyA, gg + jj);
        }
        #pragma unroll
        for (int jj = 0; jj < 8; ++jj) {
          da[jj] = dist2(qx[jj], qy[jj], sAx, sAy);
          db[jj] = dist2(qx[jj], qy[jj], sBx, sBy);
        }
        const float m8a = fminf(fminf(fminf(da[0], da[1]), fminf(da[2], da[3])),
                                fminf(fminf(da[4], da[5]), fminf(da[6], da[7])));
        const bool condA = (m8a < bd2A);
        if (__builtin_expect(__any((int)(condA && lane > gg && lane < gg + 8)), 0)) {
          // danger: exact sequential replay (A updates inside window possible)
          #pragma unroll
          for (int jj = 0; jj < 8; ++jj) {
            const int t = gg + jj;
            const float px = bcastf(nxA, t);
            const float py = bcastf(nyA, t);
            if (lane > t) {
              const float nd = dist2(px, py, sAx, sAy);
              if (nd < bd2A) {
                bd2A = nd; bxA = px; byA = py;
                steer(sAx, sAy, bd2A, bxA, byA, nxA, nyA);
              }
            }
            {
              const float nd = dist2(px, py, sBx, sBy);
              if (nd < bd2B) {
                bd2B = nd; bxB = px; byB = py;
                steer(sBx, sBy, bd2B, bxB, byB, nxB, nyB);
              }
            }
            const unsigned idx = (unsigned)(c + t + 1);
            cfold(dist2(px, py, s1Ax, s1Ay), idx, cA1d, cA1i);
            cfold(dist2(px, py, s1Bx, s1By), idx, cB1d, cB1i);
            cfold(dist2(px, py, s2Ax, s2Ay), idx, cA2d, cA2i);
            cfold(dist2(px, py, s2Bx, s2By), idx, cB2d, cB2i);
          }
        } else {
          // fast: broadcasts valid
          if (__builtin_expect(__any((int)(condA && lane >= gg + 8)), 0)) {
            if (condA && lane >= gg + 8) {
              #pragma unroll
              for (int jj = 0; jj < 8; ++jj)     // ascending strict <: exact
                if (da[jj] < bd2A) { bd2A = da[jj]; bxA = qx[jj]; byA = qy[jj]; }
              steer(sAx, sAy, bd2A, bxA, byA, nxA, nyA);
            }
          }
          const float m8b = fminf(fminf(fminf(db[0], db[1]), fminf(db[2], db[3])),
                                  fminf(fminf(db[4], db[5]), fminf(db[6], db[7])));
          const bool condB = (m8b < bd2B);       // B folds ALL A-half nodes
          if (__builtin_expect(__any((int)condB), 0)) {
            if (condB) {
              #pragma unroll
              for (int jj = 0; jj < 8; ++jj)
                if (db[jj] < bd2B) { bd2B = db[jj]; bxB = qx[jj]; byB = qy[jj]; }
              steer(sBx, sBy, bd2B, bxB, byB, nxB, nyB);
            }
          }
          #pragma unroll
          for (int jj = 0; jj < 8; ++jj) {
            const unsigned idx = (unsigned)(c + gg + jj + 1);
            cfold(dist2(qx[jj], qy[jj], s1Ax, s1Ay), idx, cA1d, cA1i);
            cfold(dist2(qx[jj], qy[jj], s1Bx, s1By), idx, cB1d, cB1i);
            cfold(dist2(qx[jj], qy[jj], s2Ax, s2Ay), idx, cA2d, cA2i);
            cfold(dist2(qx[jj], qy[jj], s2Bx, s2By), idx, cB2d, cB2i);
          }
        }
      }

      // ---- B-half: steps t=64..127, broadcasts from state B ----
      #pragma unroll
      for (int g = 8; g < 16; ++g) {
        const int gg = g * 8;
        const int gb = gg - 64;                  // B-relative base
        float qx[8], qy[8], db[8];
        #pragma unroll
        for (int jj = 0; jj < 8; ++jj) {
          qx[jj] = bcastf(nxB, gb + jj);         // node c+gg+jj+1 (speculative)
          qy[jj] = bcastf(nyB, gb + jj);
        }
        #pragma unroll
        for (int jj = 0; jj < 8; ++jj)
          db[jj] = dist2(qx[jj], qy[jj], sBx, sBy);
        const float m8b = fminf(fminf(fminf(db[0], db[1]), fminf(db[2], db[3])),
                                fminf(fminf(db[4], db[5]), fminf(db[6], db[7])));
        const bool condB = (m8b < bd2B);
        if (__builtin_expect(__any((int)(condB && lane > gb && lane < gb + 8)), 0)) {
          #pragma unroll
          for (int jj = 0; jj < 8; ++jj) {
            const int tb = gb + jj;
            const float px = bcastf(nxB, tb);
            const float py = bcastf(nyB, tb);
            if (lane > tb) {
              const float nd = dist2(px, py, sBx, sBy);
              if (nd < bd2B) {
                bd2B = nd; bxB = px; byB = py;
                steer(sBx, sBy, bd2B, bxB, byB, nxB, nyB);
              }
            }
            const unsigned idx = (unsigned)(c + 64 + tb + 1);
            cfold(dist2(px, py, s1Ax, s1Ay), idx, cA1d, cA1i);
            cfold(dist2(px, py, s1Bx, s1By), idx, cB1d, cB1i);
            cfold(dist2(px, py, s2Ax, s2Ay), idx, cA2d, cA2i);
            cfold(dist2(px, py, s2Bx, s2By), idx, cB2d, cB2i);
          }
        } else {
          if (__builtin_expect(__any((int)(condB && lane >= gb + 8)), 0)) {
            if (condB && lane >= gb + 8) {
              #pragma unroll
              for (int jj = 0; jj < 8; ++jj)
                if (db[jj] < bd2B) { bd2B = db[jj]; bxB = qx[jj]; byB = qy[jj]; }
              steer(sBx, sBy, bd2B, bxB, byB, nxB, nyB);
            }
          }
          #pragma unroll
          for (int jj = 0; jj < 8; ++jj) {
            const unsigned idx = (unsigned)(c + gg + jj + 1);
            cfold(dist2(qx[jj], qy[jj], s1Ax, s1Ay), idx, cA1d, cA1i);
            cfold(dist2(qx[jj], qy[jj], s1Bx, s1By), idx, cB1d, cB1i);
            cfold(dist2(qx[jj], qy[jj], s2Ax, s2Ay), idx, cA2d, cA2i);
            cfold(dist2(qx[jj], qy[jj], s2Bx, s2By), idx, cB2d, cB2i);
          }
        }
      }

      // publish (self-validating; no drain)
      const u64 pvA = packf2(nxA, nyA);
      const u64 pvB = packf2(nxB, nyB);
      st_agent(&outU[c + lane + 1], pvA);
      st_agent(&outU[c + 64 + lane + 1], pvB);
      st_agent(&Nb[c + lane], pvA);
      st_agent(&Nb[c + 64 + lane], pvB);

      sAx = s1Ax; sAy = s1Ay; sBx = s1Bx; sBy = s1By;
      s1Ax = s2Ax; s1Ay = s2Ay; s1Bx = s2Bx; s1By = s2By;
    }
  } else {
    // ================= scanners: blocks 1..64, 2 samples each ==============
    // iter i (0..60): wave0 issues poison-gated loads of fresh chunk i; all
    // waves bulk-scan nodes [1..128i] from global Nb (agent loads; validated
    // by this block's own earlier iters); wave0 folds node0+fresh, publishes
    // slot i&3 tag i+131 (for merge j=i+3).  ~2 chunk-periods of slack.
    const int b = blk - 1;

    for (int i = 0; i <= NCHUNKS - 4; ++i) {
      const int c = i * NCHUNK;

      u64 nv0 = POISON64, nv1 = POISON64;
      if (wave == 0) {                     // issue early, check late
        nv0 = ld_agent(&Nb[c + lane]);
        nv1 = ld_agent(&Nb[c + 64 + lane]);
      }

      // samples: chunk i+3, indices b and 64+b
      float sx0, sy0, sx1, sy1;
      {
        const int i0 = (i + 3) * NCHUNK + b;
        const float u0 = u[i0];
        if (u0 < 0.1f) { sx0 = gx; sy0 = gy; }
        else { sx0 = mul_rn(r[2 * i0], 200.0f); sy0 = mul_rn(r[2 * i0 + 1], 200.0f); }
        const int i1 = i0 + 64;
        const float u1 = u[i1];
        if (u1 < 0.1f) { sx1 = gx; sy1 = gy; }
        else { sx1 = mul_rn(r[2 * i1], 200.0f); sy1 = mul_rn(r[2 * i1 + 1], 200.0f); }
      }

      // bulk scan nodes 1..c (pairs) + node 0
      u64 k0 = mkkey(dist2(n0x, n0y, sx0, sy0), 0);
      u64 k1 = mkkey(dist2(n0x, n0y, sx1, sy1), 0);
      for (int n = 1 + 2 * tid; n < c; n += 2 * NTHREADS) {
        const u64 va = ld_agent(&Nb[n - 1]);       // node n
        const u64 vb = ld_agent(&Nb[n]);           // node n+1
        const float ax = lo32f(va), ay = hi32f(va);
        const float bx = lo32f(vb), by = hi32f(vb);
        const u64 ka0 = mkkey(dist2(ax, ay, sx0, sy0), n);
        const u64 kb0 = mkkey(dist2(bx, by, sx0, sy0), n + 1);
        const u64 ka1 = mkkey(dist2(ax, ay, sx1, sy1), n);
        const u64 kb1 = mkkey(dist2(bx, by, sx1, sy1), n + 1);
        if (ka0 < k0) k0 = ka0;
        if (kb0 < k0) k0 = kb0;
        if (ka1 < k1) k1 = ka1;
        if (kb1 < k1) k1 = kb1;
      }
      #pragma unroll
      for (int m = 32; m >= 1; m >>= 1) {
        const u64 o0 = __shfl_xor(k0, m, 64); if (o0 < k0) k0 = o0;
        const u64 o1 = __shfl_xor(k1, m, 64); if (o1 < k1) k1 = o1;
      }
      if (lane == 0) { wkey[wave][0] = k0; wkey[wave][1] = k1; }
      __syncthreads();

      if (wave == 0) {
        k0 = wkey[0][0]; k1 = wkey[0][1];
        #pragma unroll
        for (int w = 1; w < 4; ++w) {
          if (wkey[w][0] < k0) k0 = wkey[w][0];
          if (wkey[w][1] < k1) k1 = wkey[w][1];
        }
        // validate + fold fresh chunk i (2 nodes per lane)
        while (!__all((int)((nv0 != POISON64) && (nv1 != POISON64)))) {
          __builtin_amdgcn_s_sleep(1);
          nv0 = ld_agent(&Nb[c + lane]);
          nv1 = ld_agent(&Nb[c + 64 + lane]);
        }
        compiler_fence();
        {
          const float px = lo32f(nv0), py = hi32f(nv0);
          const int idx = c + lane + 1;
          const u64 t0 = mkkey(dist2(px, py, sx0, sy0), idx);
          const u64 t1 = mkkey(dist2(px, py, sx1, sy1), idx);
          if (t0 < k0) k0 = t0;
          if (t1 < k1) k1 = t1;
        }
        {
          const float px = lo32f(nv1), py = hi32f(nv1);
          const int idx = c + 64 + lane + 1;
          const u64 t0 = mkkey(dist2(px, py, sx0, sy0), idx);
          const u64 t1 = mkkey(dist2(px, py, sx1, sy1), idx);
          if (t0 < k0) k0 = t0;
          if (t1 < k1) k1 = t1;
        }
        #pragma unroll
        for (int m = 32; m >= 1; m >>= 1) {
          const u64 o0 = __shfl_xor(k0, m, 64); if (o0 < k0) k0 = o0;
          const u64 o1 = __shfl_xor(k1, m, 64); if (o1 < k1) k1 = o1;
        }
        if (lane == 0) {
          u64* slot = MbufK + (((unsigned)i) & 3u) * NCHUNK;
          const u64 tg = (u64)(unsigned)(i + 131) << 13;
          st_agent(&slot[b], k0 | tg);
          st_agent(&slot[64 + b], k1 | tg);
        }
      }
      __syncthreads();   // wkey reuse; orders validation before next bulk
    }
  }
}

extern "C" void kernel_launch(void* const* d_in, const int* in_sizes, int n_in,
                              void* d_out, int out_size, void* d_ws, size_t ws_size,
                              hipStream_t stream) {
  const float* state = (const float*)d_in[0];
  const float* goal  = (const float*)d_in[1];
  const float* u     = (const float*)d_in[2];
  const float* r     = (const float*)d_in[3];
  float* out = (float*)d_out;
  unsigned* ws = (unsigned*)d_ws;
  (void)in_sizes; (void)n_in; (void)out_size; (void)ws_size;
  rrt_kernel<<<NSCAN + 1, NTHREADS, 0, stream>>>(state, goal, u, r, out, ws);
}

// Round 7
// 917.681 us; speedup vs baseline: 1.8775x; 1.8775x over previous
//
#include <hip/hip_runtime.h>

#define MAX_ITER 8192
#define NCHUNK   64
#define NCHUNKS  128          // MAX_ITER / NCHUNK
#define NSCAN    64           // scanner blocks, 1 sample each
#define NTHREADS 256
#define MAGIC    0x13572468u

typedef unsigned long long u64;
#define KEY_MAX 0xffffffffffffffffull

// IEEE fp32 ops, contraction off -> bitwise numpy match (verified many rounds).
__device__ __forceinline__ float mul_rn(float a, float b) {
#pragma clang fp contract(off)
  return a * b;
}
__device__ __forceinline__ float add_rn(float a, float b) {
#pragma clang fp contract(off)
  return a + b;
}
__device__ __forceinline__ float sub_rn(float a, float b) {
#pragma clang fp contract(off)
  return a - b;
}
__device__ __forceinline__ float bcastf(float v, int lane) {
  return __int_as_float(__builtin_amdgcn_readlane(__float_as_int(v), lane));
}
__device__ __forceinline__ void st_agent(u64* p, u64 v) {
  __hip_atomic_store(p, v, __ATOMIC_RELAXED, __HIP_MEMORY_SCOPE_AGENT);
}
__device__ __forceinline__ u64 ld_agent(u64* p) {
  return __hip_atomic_load(p, __ATOMIC_RELAXED, __HIP_MEMORY_SCOPE_AGENT);
}
__device__ __forceinline__ void st_agent32(unsigned* p, unsigned v) {
  __hip_atomic_store(p, v, __ATOMIC_RELAXED, __HIP_MEMORY_SCOPE_AGENT);
}
__device__ __forceinline__ unsigned ld_agent32(unsigned* p) {
  return __hip_atomic_load(p, __ATOMIC_RELAXED, __HIP_MEMORY_SCOPE_AGENT);
}
__device__ __forceinline__ u64 packf2(float x, float y) {
  return ((u64)__float_as_uint(y) << 32) | (u64)__float_as_uint(x);
}
__device__ __forceinline__ void waitcnt_vm0() {
  asm volatile("s_waitcnt vmcnt(0)" ::: "memory");
}
__device__ __forceinline__ void compiler_fence() {
  asm volatile("" ::: "memory");
}
// Exact (d2, idx) lexicographic key: d2 >= 0 -> bit-monotonic; ties -> low idx.
// idx bits 0..12 (max 8064); tag bits 13..19 (k+1 in 1..127; poison tag 85
// only dangerous before slot's first write, i.e. k==1 check vs 85: != ok).
__device__ __forceinline__ u64 mkkey(float d2, int idx) {
  return ((u64)__float_as_uint(d2) << 32) | (u64)(unsigned)idx;
}

__global__ __launch_bounds__(NTHREADS) void rrt_kernel(
    const float* __restrict__ state, const float* __restrict__ goal,
    const float* __restrict__ u, const float* __restrict__ r,
    float* __restrict__ out, unsigned* __restrict__ ws) {
  // scanners: staged node copy (bulk prescan source).
  // coordinator: its OWN self-copy (M-index -> coords via ds_read, no MbufC).
  __shared__ __align__(16) float2 nodesL[8064];
  __shared__ u64 sharedK[4];

  u64* outU = (u64*)out;                // node i at outU[i] (float2-packed)
  unsigned* nflag = ws;                 // coordinator epoch       (byte 0)
  unsigned* ini   = ws + 32;            // init guard              (byte 128)
  u64* MbufK = (u64*)(ws + 64);         // 64 tagged keys          (byte 256)

  const int tid  = threadIdx.x;
  const int wave = tid >> 6;
  const int lane = tid & 63;
  const int blk  = blockIdx.x;

  const float n0x = state[0], n0y = state[1];
  const float gx = goal[0],  gy = goal[1];

  if (blk == 0) {
    // ================= coordinator: one wave, no barriers ==================
    if (tid == 0) {   // d_ws re-poisoned 0xAA each launch
      st_agent32(nflag, 0u);
      st_agent(&outU[0], packf2(n0x, n0y));   // node 0
      waitcnt_vm0();
      st_agent32(ini, MAGIC);
    }
    if (tid >= 64) return;

    // current-chunk sample (chunk 0)
    float sx, sy;
    {
      const float uu = u[lane];
      if (uu < 0.1f) { sx = gx; sy = gy; }
      else { sx = mul_rn(r[2 * lane], 200.0f); sy = mul_rn(r[2 * lane + 1], 200.0f); }
    }
    float cbd2 = 3.0e38f, cbx = 0.0f, cby = 0.0f;   // carry over (c-64, c]
    u64 kvPre = 0;                                   // speculative MbufK preload

    for (int k = 0; k < NCHUNKS; ++k) {
      const int c = k * NCHUNK;
      const bool hasNext = (k < NCHUNKS - 1);

      // prefetch next-chunk sample (independent loads; also gives the
      // in-flight kvPre time to land)
      float nsx = 0.0f, nsy = 0.0f;
      if (hasNext) {
        const int i2 = c + NCHUNK + lane;
        const float uu = u[i2];
        if (uu < 0.1f) { nsx = gx; nsy = gy; }
        else { nsx = mul_rn(r[2 * i2], 200.0f); nsy = mul_rn(r[2 * i2 + 1], 200.0f); }
      }

      // ---- assemble argmin over [0..c]: scanner M [0..c-64] + carry (c-64,c]
      float bd2, bx, by;
      if (k == 0) {
        const float dx = sub_rn(n0x, sx), dy = sub_rn(n0y, sy);
        bd2 = add_rn(mul_rn(dx, dx), mul_rn(dy, dy));
        bx = n0x; by = n0y;
      } else {
        u64 kv = kvPre;   // issued right after previous epoch's nflag store
        if (!__all((int)(((unsigned)(kv >> 13) & 0x7Fu) == (unsigned)k))) {
          for (;;) {   // fallback poll: one coalesced load, all 64 must match
            kv = ld_agent(&MbufK[lane]);
            if (__all((int)(((unsigned)(kv >> 13) & 0x7Fu) == (unsigned)k))) break;
            __builtin_amdgcn_s_sleep(1);
          }
        }
        compiler_fence();
        const float md2 = __uint_as_float((unsigned)(kv >> 32));
        const unsigned midx = (unsigned)kv & 0x1FFFu;
        bd2 = cbd2; bx = cbx; by = cby;
        if (!(bd2 < md2)) {   // M's indices are all lower: M wins ties
          bd2 = md2;
          if (midx == 0u) { bx = n0x; by = n0y; }
          else { const float2 p = nodesL[midx - 1]; bx = p.x; by = p.y; }
        }
      }

      // pre-steer (verified math)
      float dirx = sub_rn(sx, bx), diry = sub_rn(sy, by);
      float dist = __fsqrt_rn(add_rn(bd2, 1e-12f));
      float scl = (dist > 5.0f) ? __fdiv_rn(5.0f, dist) : 1.0f;
      float nx = add_rn(bx, mul_rn(dirx, scl));
      float ny = add_rn(by, mul_rn(diry, scl));

      float nbd2 = 3.0e38f, nbx = 0.0f, nby = 0.0f;   // next carry

      // ---- 64 sequential steps; r0's exact loop (no grouped speculation)
      #pragma unroll 8
      for (int t = 0; t < NCHUNK; ++t) {
        const float px = bcastf(nx, t);   // node c+t+1
        const float py = bcastf(ny, t);
        if (lane > t) {
          const float dx = sub_rn(px, sx), dy = sub_rn(py, sy);
          const float nd2 = add_rn(mul_rn(dx, dx), mul_rn(dy, dy));
          if (nd2 < bd2) {               // rare: recompute steer
            bd2 = nd2; bx = px; by = py;
            dirx = sub_rn(sx, bx); diry = sub_rn(sy, by);
            dist = __fsqrt_rn(add_rn(nd2, 1e-12f));
            scl = (dist > 5.0f) ? __fdiv_rn(5.0f, dist) : 1.0f;
            nx = add_rn(bx, mul_rn(dirx, scl));
            ny = add_rn(by, mul_rn(diry, scl));
          }
        }
        {  // carried next-chunk update (independent; hides in readlane stalls)
          const float dx = sub_rn(px, nsx), dy = sub_rn(py, nsy);
          const float nd2 = add_rn(mul_rn(dx, dx), mul_rn(dy, dy));
          if (nd2 < nbd2) { nbd2 = nd2; nbx = px; nby = py; }
        }
      }

      // publish: LDS self-copy (for M-index resolution) + global + flag
      if (c + lane < 8064) {
        float2 p; p.x = nx; p.y = ny;
        nodesL[c + lane] = p;             // node c+lane+1 at LDS idx c+lane
      }
      st_agent(&outU[c + lane + 1], packf2(nx, ny));
      waitcnt_vm0();                     // wave-level drain of all 64 stores
      if (lane == 0 && hasNext) st_agent32(nflag, (unsigned)(k + 1));
      compiler_fence();
      // speculative preload AFTER nflag (off the drain path); stale -> poll
      if (hasNext) kvPre = ld_agent(&MbufK[lane]);

      cbd2 = nbd2; cbx = nbx; cby = nby;
      sx = nsx; sy = nsy;
    }
  } else {
    // ================= scanners: blocks 1..64, one sample each =============
    // iter k -> M_{k+1} over [0..64k].  Bulk [1..64(k-1)] scanned from LDS
    // BEFORE the poll (needs nothing from this epoch); wave-0 tail polls
    // nflag>=k, loads the 64 fresh nodes (one per lane), stages + folds them,
    // publishes the tagged key.  Post-nflag chain = poll + 64-node load +
    // 1 dist + reduce + store.
    const int b = blk - 1;
    if (tid == 0) {
      while (ld_agent32(ini) != MAGIC) __builtin_amdgcn_s_sleep(2);
      compiler_fence();
    }
    __syncthreads();

    for (int k = 0; k < NCHUNKS - 1; ++k) {
      const int c  = k * NCHUNK;
      const int cb = c - NCHUNK;        // bulk top: nodes [1..cb] in LDS

      // my sample: chunk k+1, slot b
      float sx, sy;
      {
        const int i = (k + 1) * NCHUNK + b;
        const float uu = u[i];
        if (uu < 0.1f) { sx = gx; sy = gy; }
        else { sx = mul_rn(r[2 * i], 200.0f); sy = mul_rn(r[2 * i + 1], 200.0f); }
      }

      // ---- bulk scan (no dependence on current epoch) ----
      u64 key = KEY_MAX;
      if (tid == 0) {   // node 0
        const float dx = sub_rn(n0x, sx), dy = sub_rn(n0y, sy);
        key = mkkey(add_rn(mul_rn(dx, dx), mul_rn(dy, dy)), 0);
      }
      // 256 lanes stride node pairs; float4 = nodes (j, j+1), j odd
      for (int j = 1 + 2 * tid; j < cb; j += 2 * NTHREADS) {
        const float4 p = *(const float4*)&nodesL[j - 1];
        const float dxa = sub_rn(p.x, sx), dya = sub_rn(p.y, sy);
        const u64 ka = mkkey(add_rn(mul_rn(dxa, dxa), mul_rn(dya, dya)), j);
        const float dxb = sub_rn(p.z, sx), dyb = sub_rn(p.w, sy);
        const u64 kb = mkkey(add_rn(mul_rn(dxb, dxb), mul_rn(dyb, dyb)), j + 1);
        if (ka < key) key = ka;     // lower idx first: exact argmin ties
        if (kb < key) key = kb;
      }
      #pragma unroll
      for (int m = 32; m >= 1; m >>= 1) {
        const u64 ok = __shfl_xor(key, m, 64);
        if (ok < key) key = ok;
      }
      if (lane == 0) sharedK[wave] = key;
      __syncthreads();                  // barrier A: partials ready

      // ---- epoch-gated tail: wave 0 only ----
      if (wave == 0) {
        u64 kk = (lane < 4) ? sharedK[lane] : KEY_MAX;
        u64 ok = __shfl_xor(kk, 1, 64); if (ok < kk) kk = ok;
        ok = __shfl_xor(kk, 2, 64);     if (ok < kk) kk = ok;

        if (k >= 1) {   // fresh nodes (cb, c], one per lane
          while (ld_agent32(nflag) < (unsigned)k) __builtin_amdgcn_s_sleep(1);
          compiler_fence();
          const int j = cb + 1 + lane;
          const u64 nv = ld_agent(&outU[j]);
          const float px = __uint_as_float((unsigned)(nv & 0xffffffffu));
          const float py = __uint_as_float((unsigned)(nv >> 32));
          float2 p; p.x = px; p.y = py;
          nodesL[j - 1] = p;            // stage for future bulk scans
          const float dx = sub_rn(px, sx), dy = sub_rn(py, sy);
          const u64 ki = mkkey(add_rn(mul_rn(dx, dx), mul_rn(dy, dy)), j);
          if (ki < kk) kk = ki;         // (d2,idx) key: tie-break order-free
        }
        #pragma unroll
        for (int m = 32; m >= 1; m >>= 1) {
          const u64 o2 = __shfl_xor(kk, m, 64);
          if (o2 < kk) kk = o2;
        }
        if (lane == 0) {
          st_agent(&MbufK[b], kk | ((u64)(unsigned)(k + 1) << 13));
        }
      }
      // barrier B: gates next iter's bulk reads of freshly staged nodes and
      // sharedK reuse.
      __syncthreads();
    }
  }
}

extern "C" void kernel_launch(void* const* d_in, const int* in_sizes, int n_in,
                              void* d_out, int out_size, void* d_ws, size_t ws_size,
                              hipStream_t stream) {
  const float* state = (const float*)d_in[0];
  const float* goal  = (const float*)d_in[1];
  const float* u     = (const float*)d_in[2];
  const float* r     = (const float*)d_in[3];
  float* out = (float*)d_out;
  unsigned* ws = (unsigned*)d_ws;
  (void)in_sizes; (void)n_in; (void)out_size; (void)ws_size;
  rrt_kernel<<<NSCAN + 1, NTHREADS, 0, stream>>>(state, goal, u, r, out, ws);
}